// Round 10
// baseline (348.494 us; speedup 1.0000x reference)
//
#include <hip/hip_runtime.h>
#include <hip/hip_fp16.h>

#define N_USER 50000
#define N_ITEM 100000
#define NTOT   150000          // N_USER + N_ITEM
#define NNZ    3000000
#define EMB    64
#define BATCH  4096

#define BROWS  128             // rows per bucket
#define NB     1172            // ceil(150000/128)
#define BCAP   3008            // mean 2560, sd ~51 -> +8.8 sigma
#define CHUNK  6144            // edges per LDS sub-stage in k_bucket
#define WIN    12288           // edges per k_bucket block (2 sub-stages, 1 reserve)

typedef unsigned short u16;
typedef unsigned int   u32;
typedef unsigned long long u64;
typedef _Float16 f16;
typedef f16   f16x8 __attribute__((ext_vector_type(8)));
typedef float f32x4 __attribute__((ext_vector_type(4)));

// ---------------------------------------------------------------------------
// ego(f16) = concat(user_emb, item_emb)   (round-8 proven form)
// ---------------------------------------------------------------------------
__global__ __launch_bounds__(256) void k_init_ego(const float4* __restrict__ ue,
                                                  const float4* __restrict__ ie,
                                                  uint2* __restrict__ ego) {
    int i = blockIdx.x * 256 + threadIdx.x;
    const int UF4 = N_USER * EMB / 4;     // 800000
    float4 f = (i < UF4) ? ue[i] : ie[i - UF4];
    __half2 h0 = __floats2half2_rn(f.x, f.y);
    __half2 h1 = __floats2half2_rn(f.z, f.w);
    ego[i] = make_uint2(*(u32*)&h0, *(u32*)&h1);
}

// ---------------------------------------------------------------------------
// out[i][:] = user_emb[users[i]][:]   (layer-0 contribution, exact fp32)
// ---------------------------------------------------------------------------
__global__ __launch_bounds__(256) void k_init_out(const float* __restrict__ ue,
                                                  const int* __restrict__ users,
                                                  float* __restrict__ out) {
    int t = blockIdx.x * 256 + threadIdx.x;
    int w = t >> 6, lane = t & 63;
    int u = users[w];
    out[w * EMB + lane] = ue[(size_t)u * EMB + lane];
}

// ---------------------------------------------------------------------------
// exclusive scan of src[0..NB) into dst[0..NB), 1024 threads (16 waves)
// ---------------------------------------------------------------------------
__device__ __forceinline__ void scan_excl(const int* src, int* dst, int* wsum,
                                          int tid, int lane, int w) {
    int carry = 0;
    for (int base = 0; base < NB; base += 1024) {
        int i = base + tid;
        int x = (i < NB) ? src[i] : 0;
        int v = x;
#pragma unroll
        for (int off = 1; off < 64; off <<= 1) {
            int y = __shfl_up(v, off);
            if (lane >= off) v += y;
        }
        if (lane == 63) wsum[w] = v;
        __syncthreads();
        if (tid < 16) {
            int s = wsum[tid];
#pragma unroll
            for (int off = 1; off < 16; off <<= 1) {
                int y = __shfl_up(s, off);
                if (tid >= off) s += y;
            }
            wsum[tid] = s;
        }
        __syncthreads();
        int excl = carry + (w ? wsum[w - 1] : 0) + v - x;
        if (i < NB) dst[i] = excl;
        carry += wsum[15];
        __syncthreads();
    }
}

// ---------------------------------------------------------------------------
// Bucket edges by row>>7, double-window, 1024 threads (round-8 proven form).
// pack: x = col | (row&127)<<18 ; y = val bits
// LDS: stage 48K + sbuck 12K + 4*NB*4=18.3K ~= 78.8 KB.
// ---------------------------------------------------------------------------
__global__ __launch_bounds__(1024) void k_bucket(const int* __restrict__ rows,
                                                 const int* __restrict__ cols,
                                                 const float* __restrict__ vals,
                                                 int* __restrict__ bcnt,      // stride 16 (line-padded)
                                                 int2* __restrict__ bbuf) {
    __shared__ int2 stage[CHUNK];      // 48 KB packed pairs, bucket-sorted
    __shared__ u16  sbuck[CHUNK];      // 12 KB bucket id per staged slot
    __shared__ int histA[NB], histB[NB], cur[NB], gbase[NB];
    __shared__ int wsum[16];
    int tid = threadIdx.x, lane = tid & 63, w = tid >> 6;
    int start = blockIdx.x * WIN;
    int s2    = start + CHUNK;
    int n1 = min(start + CHUNK, NNZ) - start; n1 = n1 < 0 ? 0 : n1;
    int n2 = min(s2 + CHUNK, NNZ) - s2;       n2 = n2 < 0 ? 0 : n2;

    for (int i = tid; i < NB; i += 1024) { histA[i] = 0; histB[i] = 0; }
    __syncthreads();
    for (int i = tid; i < n1; i += 1024)
        atomicAdd(&histA[rows[start + i] >> 7], 1);
    for (int i = tid; i < n2; i += 1024)
        atomicAdd(&histB[rows[s2 + i] >> 7], 1);
    __syncthreads();

    // reserve ONE global run per bucket covering both sub-stages
    for (int i = tid; i < NB; i += 1024) {
        int t = histA[i] + histB[i];
        gbase[i] = t ? atomicAdd(&bcnt[i * 16], t) : 0;
    }
    scan_excl(histA, cur, wsum, tid, lane, w);

    // ---- sub-stage 1 ----
    for (int i = tid; i < n1; i += 1024) {
        int e = start + i;
        int r = rows[e];
        int b = r >> 7;
        int pos = atomicAdd(&cur[b], 1);
        stage[pos] = make_int2(cols[e] | ((r & 127) << 18), __float_as_int(vals[e]));
        sbuck[pos] = (u16)b;
    }
    __syncthreads();
    // after scatter: cur[b] = exclA[b] + histA[b]  ->  base = cur[b]-histA[b]
    for (int j = tid; j < n1; j += 1024) {
        int b = sbuck[j];
        int pos = gbase[b] + (j - (cur[b] - histA[b]));
        if (pos < BCAP)
            bbuf[(size_t)b * BCAP + pos] = stage[j];
    }
    __syncthreads();

    // ---- sub-stage 2 ----
    scan_excl(histB, cur, wsum, tid, lane, w);
    for (int i = tid; i < n2; i += 1024) {
        int e = s2 + i;
        int r = rows[e];
        int b = r >> 7;
        int pos = atomicAdd(&cur[b], 1);
        stage[pos] = make_int2(cols[e] | ((r & 127) << 18), __float_as_int(vals[e]));
        sbuck[pos] = (u16)b;
    }
    __syncthreads();
    for (int j = tid; j < n2; j += 1024) {
        int b = sbuck[j];
        int pos = gbase[b] + histA[b] + (j - (cur[b] - histB[b]));
        if (pos < BCAP)
            bbuf[(size_t)b * BCAP + pos] = stage[j];
    }
}

// ---------------------------------------------------------------------------
// Fused layer, one block per 128-row bucket, 512 threads (8 waves). CSR form.
// THIS ROUND'S single experiment: nt hints confined to this kernel.
//  - edge-stream reads (phases 0a/0c): nontemporal (24 MB/dispatch, read
//    once -> keep out of the 4-MB per-XCD L2s so ego keeps more of them)
//  - ego_out stores: nontemporal (19.2 MB write-allocate pollution)
//  - ego gather loads: NORMAL (the data we want cached)
// Round-8 lesson: more in-flight gathers was a null -> bound by L2-miss
// handling (FETCH 163 MB vs ~142 MB floor); pollution is the lever left.
// Phase 0: LDS counting-sort of the bucket's edges by row.
// Phase 1: 2 interleaved rows/lane-group, 2-deep, f32 register FMA.
// Phase 2: MFMA dense: side(128x64) @ W(64x64 f16) + bias, leaky_relu, f16.
// LDS: stg 24K + S16 18K + Wl 9K + ctl ~1.6K = 52.8 KB -> 3 blocks/CU.
// ---------------------------------------------------------------------------
__global__ __launch_bounds__(512) void k_fused(const int* __restrict__ bcnt,
                                               const int2* __restrict__ bbuf,
                                               const f16* __restrict__ ego_in,
                                               const float* __restrict__ W,
                                               const float* __restrict__ bias,
                                               u16* __restrict__ ego_out) {
    __shared__ int2 stg[BCAP];          // row-sorted edges
    __shared__ f16  S16[BROWS * 72];    // side tile, f16, stride 72 (16B-aligned rows)
    __shared__ f16  Wl[64 * 72];        // Wl[n][k], stride 72
    __shared__ int  hist[128], cur[128], rowptr[129];
    __shared__ int  ws2[2];
    int tid = threadIdx.x, lane = tid & 63, w = tid >> 6;

    int b = blockIdx.x;
    int cnt = min(bcnt[b * 16], BCAP);
    const u64* srcq = (const u64*)(bbuf + (size_t)b * BCAP);

    for (int i = tid; i < 4096; i += 512) {       // i = k*64 + n
        int k = i >> 6, n = i & 63;
        Wl[n * 72 + k] = (f16)W[i];
    }
    if (tid < 128) hist[tid] = 0;
    __syncthreads();

    // phase 0a: row histogram (row bits 18..24 of packed x) — nt edge reads
    for (int i = tid; i < cnt; i += 512) {
        u64 pe = __builtin_nontemporal_load(srcq + i);
        atomicAdd(&hist[(int)((pe >> 18) & 127)], 1);
    }
    __syncthreads();

    // phase 0b: exclusive scan of 128 bins (2 waves + fixup)
    int sx = 0, sv = 0;
    if (tid < 128) {
        sx = hist[tid]; sv = sx;
#pragma unroll
        for (int off = 1; off < 64; off <<= 1) {
            int y = __shfl_up(sv, off);
            if (lane >= off) sv += y;
        }
        if (lane == 63) ws2[tid >> 6] = sv;
    }
    __syncthreads();
    if (tid < 128) {
        int excl = sv - sx + ((tid >= 64) ? ws2[0] : 0);
        rowptr[tid] = excl;
        cur[tid]    = excl;
    }
    if (tid == 0) rowptr[128] = cnt;
    __syncthreads();

    // phase 0c: scatter edges into row-sorted LDS — nt edge reads
    for (int i = tid; i < cnt; i += 512) {
        u64 pe = __builtin_nontemporal_load(srcq + i);
        int2 e;
        e.x = (int)(u32)pe;
        e.y = (int)(u32)(pe >> 32);
        int pos = atomicAdd(&cur[(int)((pe >> 18) & 127)], 1);
        stg[pos] = e;
    }
    __syncthreads();

    // phase 1: CSR register accumulation, two interleaved rows per lane.
    const char* egob = (const char*)ego_in;
    int slot = lane >> 3, d8 = lane & 7;
    int rA = w * 16 + slot;
    int rB = rA + 8;
    int eA = rowptr[rA], kA = rowptr[rA + 1];
    int eB = rowptr[rB], kB = rowptr[rB + 1];
    float accA[8], accB[8];
#pragma unroll
    for (int j = 0; j < 8; ++j) { accA[j] = 0.f; accB[j] = 0.f; }
    while (__any((eA < kA) || (eB < kB))) {
        bool a0 = eA < kA, a1 = (eA + 1) < kA;
        bool b0 = eB < kB, b1 = (eB + 1) < kB;
        uint4 gA0, gA1, gB0, gB1;
        float vA0 = 0.f, vA1 = 0.f, vB0 = 0.f, vB1 = 0.f;
        if (a0) {
            int2 p = stg[eA];
            gA0 = *(const uint4*)(egob + ((size_t)(p.x & 0x3FFFF) << 7) + d8 * 16);
            vA0 = __int_as_float(p.y);
        }
        if (a1) {
            int2 p = stg[eA + 1];
            gA1 = *(const uint4*)(egob + ((size_t)(p.x & 0x3FFFF) << 7) + d8 * 16);
            vA1 = __int_as_float(p.y);
        }
        if (b0) {
            int2 p = stg[eB];
            gB0 = *(const uint4*)(egob + ((size_t)(p.x & 0x3FFFF) << 7) + d8 * 16);
            vB0 = __int_as_float(p.y);
        }
        if (b1) {
            int2 p = stg[eB + 1];
            gB1 = *(const uint4*)(egob + ((size_t)(p.x & 0x3FFFF) << 7) + d8 * 16);
            vB1 = __int_as_float(p.y);
        }
        if (a0) {
            float2 f0 = __half22float2(*(const __half2*)&gA0.x);
            float2 f1 = __half22float2(*(const __half2*)&gA0.y);
            float2 f2 = __half22float2(*(const __half2*)&gA0.z);
            float2 f3 = __half22float2(*(const __half2*)&gA0.w);
            accA[0] = fmaf(vA0, f0.x, accA[0]); accA[1] = fmaf(vA0, f0.y, accA[1]);
            accA[2] = fmaf(vA0, f1.x, accA[2]); accA[3] = fmaf(vA0, f1.y, accA[3]);
            accA[4] = fmaf(vA0, f2.x, accA[4]); accA[5] = fmaf(vA0, f2.y, accA[5]);
            accA[6] = fmaf(vA0, f3.x, accA[6]); accA[7] = fmaf(vA0, f3.y, accA[7]);
        }
        if (a1) {
            float2 f0 = __half22float2(*(const __half2*)&gA1.x);
            float2 f1 = __half22float2(*(const __half2*)&gA1.y);
            float2 f2 = __half22float2(*(const __half2*)&gA1.z);
            float2 f3 = __half22float2(*(const __half2*)&gA1.w);
            accA[0] = fmaf(vA1, f0.x, accA[0]); accA[1] = fmaf(vA1, f0.y, accA[1]);
            accA[2] = fmaf(vA1, f1.x, accA[2]); accA[3] = fmaf(vA1, f1.y, accA[3]);
            accA[4] = fmaf(vA1, f2.x, accA[4]); accA[5] = fmaf(vA1, f2.y, accA[5]);
            accA[6] = fmaf(vA1, f3.x, accA[6]); accA[7] = fmaf(vA1, f3.y, accA[7]);
        }
        if (b0) {
            float2 f0 = __half22float2(*(const __half2*)&gB0.x);
            float2 f1 = __half22float2(*(const __half2*)&gB0.y);
            float2 f2 = __half22float2(*(const __half2*)&gB0.z);
            float2 f3 = __half22float2(*(const __half2*)&gB0.w);
            accB[0] = fmaf(vB0, f0.x, accB[0]); accB[1] = fmaf(vB0, f0.y, accB[1]);
            accB[2] = fmaf(vB0, f1.x, accB[2]); accB[3] = fmaf(vB0, f1.y, accB[3]);
            accB[4] = fmaf(vB0, f2.x, accB[4]); accB[5] = fmaf(vB0, f2.y, accB[5]);
            accB[6] = fmaf(vB0, f3.x, accB[6]); accB[7] = fmaf(vB0, f3.y, accB[7]);
        }
        if (b1) {
            float2 f0 = __half22float2(*(const __half2*)&gB1.x);
            float2 f1 = __half22float2(*(const __half2*)&gB1.y);
            float2 f2 = __half22float2(*(const __half2*)&gB1.z);
            float2 f3 = __half22float2(*(const __half2*)&gB1.w);
            accB[0] = fmaf(vB1, f0.x, accB[0]); accB[1] = fmaf(vB1, f0.y, accB[1]);
            accB[2] = fmaf(vB1, f1.x, accB[2]); accB[3] = fmaf(vB1, f1.y, accB[3]);
            accB[4] = fmaf(vB1, f2.x, accB[4]); accB[5] = fmaf(vB1, f2.y, accB[5]);
            accB[6] = fmaf(vB1, f3.x, accB[6]); accB[7] = fmaf(vB1, f3.y, accB[7]);
        }
        eA += 2; eB += 2;
    }
    {
        f16x8 hA, hB;
#pragma unroll
        for (int j = 0; j < 8; ++j) { hA[j] = (f16)accA[j]; hB[j] = (f16)accB[j]; }
        *(f16x8*)&S16[rA * 72 + d8 * 8] = hA;
        *(f16x8*)&S16[rB * 72 + d8 * 8] = hB;
    }
    __syncthreads();

    // phase 2: MFMA epilogue. 8 waves x 16 rows -> 128 rows. nt stores.
    int m = lane & 15, quad = lane >> 4;
    int rowbase = b * BROWS;
    int m0 = w * 16;
    f32x4 C[4] = {{0.f,0.f,0.f,0.f},{0.f,0.f,0.f,0.f},{0.f,0.f,0.f,0.f},{0.f,0.f,0.f,0.f}};
#pragma unroll
    for (int kk = 0; kk < 2; ++kk) {
        f16x8 A = *(const f16x8*)&S16[(m0 + m) * 72 + kk * 32 + quad * 8];
#pragma unroll
        for (int nt = 0; nt < 4; ++nt) {
            f16x8 B = *(const f16x8*)&Wl[(nt * 16 + m) * 72 + kk * 32 + quad * 8];
            C[nt] = __builtin_amdgcn_mfma_f32_16x16x32_f16(A, B, C[nt], 0, 0, 0);
        }
    }
#pragma unroll
    for (int nt = 0; nt < 4; ++nt) {
        float bv = bias[nt * 16 + m];
#pragma unroll
        for (int r = 0; r < 4; ++r) {
            int orow = rowbase + m0 + quad * 4 + r;
            float o = C[nt][r] + bv;
            o = o > 0.f ? o : 0.2f * o;
            if (orow < NTOT) {
                __half hh = __float2half(o);
                __builtin_nontemporal_store(*(u16*)&hh,
                    &ego_out[(size_t)orow * EMB + nt * 16 + m]);
            }
        }
    }
}

// ---------------------------------------------------------------------------
// out[i][:] += l2norm(ego_f16[users[i]][:])
// ---------------------------------------------------------------------------
__global__ __launch_bounds__(256) void k_accum(const __half* __restrict__ ego,
                                               const int* __restrict__ users,
                                               float* __restrict__ out) {
    int t = blockIdx.x * 256 + threadIdx.x;
    int w = t >> 6, lane = t & 63;
    int u = users[w];
    float x = __half2float(ego[(size_t)u * EMB + lane]);
    float ss = x * x;
#pragma unroll
    for (int off = 32; off; off >>= 1) ss += __shfl_xor(ss, off);
    float n = sqrtf(ss);
    out[w * EMB + lane] += x / fmaxf(n, 1e-12f);
}

// ---------------------------------------------------------------------------
extern "C" void kernel_launch(void* const* d_in, const int* in_sizes, int n_in,
                              void* d_out, int out_size, void* d_ws, size_t ws_size,
                              hipStream_t stream) {
    const int*   users = (const int*)d_in[0];
    const int*   rows  = (const int*)d_in[1];
    const int*   cols  = (const int*)d_in[2];
    const float* vals  = (const float*)d_in[3];
    const float* ue    = (const float*)d_in[4];
    const float* ie    = (const float*)d_in[5];
    const float* Ws[3] = {(const float*)d_in[6], (const float*)d_in[8], (const float*)d_in[10]};
    const float* bs[3] = {(const float*)d_in[7], (const float*)d_in[9], (const float*)d_in[11]};
    float* out = (float*)d_out;

    // workspace layout (bytes, all 16B-aligned) — identical to round-0 footprint
    char* p = (char*)d_ws;
    f16*  egoA  = (f16*)p;  p += (size_t)NTOT * EMB * 2;        // 19.2 MB
    f16*  egoB  = (f16*)p;  p += (size_t)NTOT * EMB * 2;        // 19.2 MB
    int2* bbuf  = (int2*)p; p += (size_t)NB * BCAP * 8;         // 28.2 MB
    int*  bcnt  = (int*)p;  p += (size_t)NB * 16 * 4;           // 75 KB (line-padded)

    hipMemsetAsync(bcnt, 0, (size_t)NB * 16 * 4, stream);
    k_init_ego<<<NTOT * EMB / 4 / 256, 256, 0, stream>>>(
        (const float4*)ue, (const float4*)ie, (uint2*)egoA);
    k_init_out<<<(BATCH * EMB) / 256, 256, 0, stream>>>(ue, users, out);

    // bucket by row>>7 (once, reused 3x), double-window, 16 waves/block
    k_bucket<<<(NNZ + WIN - 1) / WIN, 1024, 0, stream>>>(rows, cols, vals, bcnt, bbuf);

    // layer 3 only needs user rows -> only the first 391 buckets
    const int grids[3] = {NB, NB, (N_USER + BROWS - 1) / BROWS};
    f16* bufs[2] = {egoA, egoB};
    for (int l = 0; l < 3; ++l) {
        const f16* src = bufs[l & 1];
        f16*       dst = bufs[(l + 1) & 1];
        k_fused<<<grids[l], 512, 0, stream>>>(bcnt, bbuf, src, Ws[l], bs[l], (u16*)dst);
        k_accum<<<(BATCH * EMB) / 256, 256, 0, stream>>>((const __half*)dst, users, out);
    }
}

// Round 11
// 318.103 us; speedup vs baseline: 1.0955x; 1.0955x over previous
//
#include <hip/hip_runtime.h>
#include <hip/hip_fp16.h>

#define N_USER 50000
#define N_ITEM 100000
#define NTOT   150000          // N_USER + N_ITEM
#define NNZ    3000000
#define EMB    64
#define BATCH  4096

#define BROWS  128             // rows per bucket
#define NB     1172            // ceil(150000/128)
#define BCAP   3008            // mean 2560, sd ~51 -> +8.8 sigma; 6*512 >= 3008
#define CHUNK  6144            // edges per LDS sub-stage in k_bucket
#define WIN    12288           // edges per k_bucket block (2 sub-stages, 1 reserve)
#define EGO_BLKS 9375          // NTOT*EMB/4/256

typedef unsigned short u16;
typedef unsigned int   u32;
typedef unsigned long long u64;
typedef _Float16 f16;
typedef f16   f16x8 __attribute__((ext_vector_type(8)));
typedef float f32x4 __attribute__((ext_vector_type(4)));

// ---------------------------------------------------------------------------
// fused init: blocks [0,EGO_BLKS) build ego(f16); the rest do the layer-0
// out[i][:] = user_emb[users[i]][:] copy. One dispatch instead of two.
// ---------------------------------------------------------------------------
__global__ __launch_bounds__(256) void k_init(const float4* __restrict__ ue4,
                                              const float4* __restrict__ ie4,
                                              uint2* __restrict__ ego,
                                              const float* __restrict__ ue,
                                              const int* __restrict__ users,
                                              float* __restrict__ out) {
    int bi = blockIdx.x, tid = threadIdx.x;
    if (bi < EGO_BLKS) {
        int i = bi * 256 + tid;
        const int UF4 = N_USER * EMB / 4;     // 800000
        float4 f = (i < UF4) ? ue4[i] : ie4[i - UF4];
        __half2 h0 = __floats2half2_rn(f.x, f.y);
        __half2 h1 = __floats2half2_rn(f.z, f.w);
        ego[i] = make_uint2(*(u32*)&h0, *(u32*)&h1);
    } else {
        int t = (bi - EGO_BLKS) * 256 + tid;
        int w = t >> 6, lane = t & 63;
        int u = users[w];
        out[w * EMB + lane] = ue[(size_t)u * EMB + lane];
    }
}

// ---------------------------------------------------------------------------
// exclusive scan of src[0..NB) into dst[0..NB), 1024 threads (16 waves)
// ---------------------------------------------------------------------------
__device__ __forceinline__ void scan_excl(const int* src, int* dst, int* wsum,
                                          int tid, int lane, int w) {
    int carry = 0;
    for (int base = 0; base < NB; base += 1024) {
        int i = base + tid;
        int x = (i < NB) ? src[i] : 0;
        int v = x;
#pragma unroll
        for (int off = 1; off < 64; off <<= 1) {
            int y = __shfl_up(v, off);
            if (lane >= off) v += y;
        }
        if (lane == 63) wsum[w] = v;
        __syncthreads();
        if (tid < 16) {
            int s = wsum[tid];
#pragma unroll
            for (int off = 1; off < 16; off <<= 1) {
                int y = __shfl_up(s, off);
                if (tid >= off) s += y;
            }
            wsum[tid] = s;
        }
        __syncthreads();
        int excl = carry + (w ? wsum[w - 1] : 0) + v - x;
        if (i < NB) dst[i] = excl;
        carry += wsum[15];
        __syncthreads();
    }
}

// ---------------------------------------------------------------------------
// Bucket edges by row>>7, double-window, 1024 threads. v5: register-staged —
// each thread loads its 12 window edges (rows+cols+vals) ONCE into registers
// (36 VGPRs), histograms from regs, scatters from regs. Removes the second
// global read of rows/cols/vals (round-8 form read rows 2x, cols/vals 1x in
// a separate pass).
// pack: x = col | (row&127)<<18 ; y = val bits
// LDS: stage 48K + sbuck 12K + 4*NB*4=18.3K ~= 78.8 KB.
// ---------------------------------------------------------------------------
__global__ __launch_bounds__(1024) void k_bucket(const int* __restrict__ rows,
                                                 const int* __restrict__ cols,
                                                 const float* __restrict__ vals,
                                                 int* __restrict__ bcnt,      // stride 16 (line-padded)
                                                 int2* __restrict__ bbuf) {
    __shared__ int2 stage[CHUNK];      // 48 KB packed pairs, bucket-sorted
    __shared__ u16  sbuck[CHUNK];      // 12 KB bucket id per staged slot
    __shared__ int histA[NB], histB[NB], cur[NB], gbase[NB];
    __shared__ int wsum[16];
    int tid = threadIdx.x, lane = tid & 63, w = tid >> 6;
    int start = blockIdx.x * WIN;
    int s2    = start + CHUNK;
    int n1 = min(start + CHUNK, NNZ) - start; n1 = n1 < 0 ? 0 : n1;
    int n2 = min(s2 + CHUNK, NNZ) - s2;       n2 = n2 < 0 ? 0 : n2;

    for (int i = tid; i < NB; i += 1024) { histA[i] = 0; histB[i] = 0; }
    __syncthreads();

    // load all 12 edges/thread into regs + histogram (single global read)
    u32 ex[12], ev[12];
    int eb[12];
#pragma unroll
    for (int u = 0; u < 6; ++u) {
        int i = u * 1024 + tid;
        if (i < n1) {
            int e = start + i;
            int r = rows[e];
            ex[u] = (u32)cols[e] | ((u32)(r & 127) << 18);
            ev[u] = (u32)__float_as_int(vals[e]);
            eb[u] = r >> 7;
            atomicAdd(&histA[eb[u]], 1);
        }
    }
#pragma unroll
    for (int u = 0; u < 6; ++u) {
        int i = u * 1024 + tid;
        if (i < n2) {
            int e = s2 + i;
            int r = rows[e];
            ex[u + 6] = (u32)cols[e] | ((u32)(r & 127) << 18);
            ev[u + 6] = (u32)__float_as_int(vals[e]);
            eb[u + 6] = r >> 7;
            atomicAdd(&histB[eb[u + 6]], 1);
        }
    }
    __syncthreads();

    // reserve ONE global run per bucket covering both sub-stages
    for (int i = tid; i < NB; i += 1024) {
        int t = histA[i] + histB[i];
        gbase[i] = t ? atomicAdd(&bcnt[i * 16], t) : 0;
    }
    scan_excl(histA, cur, wsum, tid, lane, w);

    // ---- sub-stage 1: scatter from regs ----
#pragma unroll
    for (int u = 0; u < 6; ++u) {
        int i = u * 1024 + tid;
        if (i < n1) {
            int pos = atomicAdd(&cur[eb[u]], 1);
            stage[pos] = make_int2((int)ex[u], (int)ev[u]);
            sbuck[pos] = (u16)eb[u];
        }
    }
    __syncthreads();
    // after scatter: cur[b] = exclA[b] + histA[b]  ->  base = cur[b]-histA[b]
    for (int j = tid; j < n1; j += 1024) {
        int b = sbuck[j];
        int pos = gbase[b] + (j - (cur[b] - histA[b]));
        if (pos < BCAP)
            bbuf[(size_t)b * BCAP + pos] = stage[j];
    }
    __syncthreads();

    // ---- sub-stage 2 ----
    scan_excl(histB, cur, wsum, tid, lane, w);
#pragma unroll
    for (int u = 0; u < 6; ++u) {
        int i = u * 1024 + tid;
        if (i < n2) {
            int pos = atomicAdd(&cur[eb[u + 6]], 1);
            stage[pos] = make_int2((int)ex[u + 6], (int)ev[u + 6]);
            sbuck[pos] = (u16)eb[u + 6];
        }
    }
    __syncthreads();
    for (int j = tid; j < n2; j += 1024) {
        int b = sbuck[j];
        int pos = gbase[b] + histA[b] + (j - (cur[b] - histB[b]));
        if (pos < BCAP)
            bbuf[(size_t)b * BCAP + pos] = stage[j];
    }
}

// ---------------------------------------------------------------------------
// Fused layer, one block per 128-row bucket, 512 threads (8 waves). CSR form.
// v3: register-staged phase 0 — each thread loads its <=6 bucket edges ONCE
// (12 VGPRs), histograms and scatters from regs. Halves the bbuf read
// (round-10 read it twice: 48 MB/dispatch). nt hints REMOVED (round-10:
// FETCH unchanged, WRITE +11 MB, dur +2 us -> falsified).
// Phase 1: 2 interleaved rows/lane-group, 2-deep, f32 register FMA.
// Phase 2: MFMA dense: side(128x64) @ W(64x64 f16) + bias, leaky_relu, f16.
// LDS: stg 24K + S16 18K + Wl 9K + ctl ~1.6K = 52.8 KB -> 3 blocks/CU.
// ---------------------------------------------------------------------------
__global__ __launch_bounds__(512) void k_fused(const int* __restrict__ bcnt,
                                               const int2* __restrict__ bbuf,
                                               const f16* __restrict__ ego_in,
                                               const float* __restrict__ W,
                                               const float* __restrict__ bias,
                                               u16* __restrict__ ego_out) {
    __shared__ int2 stg[BCAP];          // row-sorted edges
    __shared__ f16  S16[BROWS * 72];    // side tile, f16, stride 72 (16B-aligned rows)
    __shared__ f16  Wl[64 * 72];        // Wl[n][k], stride 72
    __shared__ int  hist[128], cur[128], rowptr[129];
    __shared__ int  ws2[2];
    int tid = threadIdx.x, lane = tid & 63, w = tid >> 6;

    int b = blockIdx.x;
    int cnt = min(bcnt[b * 16], BCAP);
    const int2* src = bbuf + (size_t)b * BCAP;

    for (int i = tid; i < 4096; i += 512) {       // i = k*64 + n
        int k = i >> 6, n = i & 63;
        Wl[n * 72 + k] = (f16)W[i];
    }
    if (tid < 128) hist[tid] = 0;
    __syncthreads();

    // phase 0a: load bucket edges ONCE into regs + histogram (bits 18..24)
    u32 fx[6], fv[6];
#pragma unroll
    for (int u = 0; u < 6; ++u) {
        int i = u * 512 + tid;
        if (i < cnt) {
            int2 e = src[i];
            fx[u] = (u32)e.x;
            fv[u] = (u32)e.y;
            atomicAdd(&hist[(fx[u] >> 18) & 127], 1);
        }
    }
    __syncthreads();

    // phase 0b: exclusive scan of 128 bins (2 waves + fixup)
    int sx = 0, sv = 0;
    if (tid < 128) {
        sx = hist[tid]; sv = sx;
#pragma unroll
        for (int off = 1; off < 64; off <<= 1) {
            int y = __shfl_up(sv, off);
            if (lane >= off) sv += y;
        }
        if (lane == 63) ws2[tid >> 6] = sv;
    }
    __syncthreads();
    if (tid < 128) {
        int excl = sv - sx + ((tid >= 64) ? ws2[0] : 0);
        rowptr[tid] = excl;
        cur[tid]    = excl;
    }
    if (tid == 0) rowptr[128] = cnt;
    __syncthreads();

    // phase 0c: scatter edges into row-sorted LDS from regs
#pragma unroll
    for (int u = 0; u < 6; ++u) {
        int i = u * 512 + tid;
        if (i < cnt) {
            int pos = atomicAdd(&cur[(fx[u] >> 18) & 127], 1);
            stg[pos] = make_int2((int)fx[u], (int)fv[u]);
        }
    }
    __syncthreads();

    // phase 1: CSR register accumulation, two interleaved rows per lane.
    const char* egob = (const char*)ego_in;
    int slot = lane >> 3, d8 = lane & 7;
    int rA = w * 16 + slot;
    int rB = rA + 8;
    int eA = rowptr[rA], kA = rowptr[rA + 1];
    int eB = rowptr[rB], kB = rowptr[rB + 1];
    float accA[8], accB[8];
#pragma unroll
    for (int j = 0; j < 8; ++j) { accA[j] = 0.f; accB[j] = 0.f; }
    while (__any((eA < kA) || (eB < kB))) {
        bool a0 = eA < kA, a1 = (eA + 1) < kA;
        bool b0 = eB < kB, b1 = (eB + 1) < kB;
        uint4 gA0, gA1, gB0, gB1;
        float vA0 = 0.f, vA1 = 0.f, vB0 = 0.f, vB1 = 0.f;
        if (a0) {
            int2 p = stg[eA];
            gA0 = *(const uint4*)(egob + ((size_t)(p.x & 0x3FFFF) << 7) + d8 * 16);
            vA0 = __int_as_float(p.y);
        }
        if (a1) {
            int2 p = stg[eA + 1];
            gA1 = *(const uint4*)(egob + ((size_t)(p.x & 0x3FFFF) << 7) + d8 * 16);
            vA1 = __int_as_float(p.y);
        }
        if (b0) {
            int2 p = stg[eB];
            gB0 = *(const uint4*)(egob + ((size_t)(p.x & 0x3FFFF) << 7) + d8 * 16);
            vB0 = __int_as_float(p.y);
        }
        if (b1) {
            int2 p = stg[eB + 1];
            gB1 = *(const uint4*)(egob + ((size_t)(p.x & 0x3FFFF) << 7) + d8 * 16);
            vB1 = __int_as_float(p.y);
        }
        if (a0) {
            float2 f0 = __half22float2(*(const __half2*)&gA0.x);
            float2 f1 = __half22float2(*(const __half2*)&gA0.y);
            float2 f2 = __half22float2(*(const __half2*)&gA0.z);
            float2 f3 = __half22float2(*(const __half2*)&gA0.w);
            accA[0] = fmaf(vA0, f0.x, accA[0]); accA[1] = fmaf(vA0, f0.y, accA[1]);
            accA[2] = fmaf(vA0, f1.x, accA[2]); accA[3] = fmaf(vA0, f1.y, accA[3]);
            accA[4] = fmaf(vA0, f2.x, accA[4]); accA[5] = fmaf(vA0, f2.y, accA[5]);
            accA[6] = fmaf(vA0, f3.x, accA[6]); accA[7] = fmaf(vA0, f3.y, accA[7]);
        }
        if (a1) {
            float2 f0 = __half22float2(*(const __half2*)&gA1.x);
            float2 f1 = __half22float2(*(const __half2*)&gA1.y);
            float2 f2 = __half22float2(*(const __half2*)&gA1.z);
            float2 f3 = __half22float2(*(const __half2*)&gA1.w);
            accA[0] = fmaf(vA1, f0.x, accA[0]); accA[1] = fmaf(vA1, f0.y, accA[1]);
            accA[2] = fmaf(vA1, f1.x, accA[2]); accA[3] = fmaf(vA1, f1.y, accA[3]);
            accA[4] = fmaf(vA1, f2.x, accA[4]); accA[5] = fmaf(vA1, f2.y, accA[5]);
            accA[6] = fmaf(vA1, f3.x, accA[6]); accA[7] = fmaf(vA1, f3.y, accA[7]);
        }
        if (b0) {
            float2 f0 = __half22float2(*(const __half2*)&gB0.x);
            float2 f1 = __half22float2(*(const __half2*)&gB0.y);
            float2 f2 = __half22float2(*(const __half2*)&gB0.z);
            float2 f3 = __half22float2(*(const __half2*)&gB0.w);
            accB[0] = fmaf(vB0, f0.x, accB[0]); accB[1] = fmaf(vB0, f0.y, accB[1]);
            accB[2] = fmaf(vB0, f1.x, accB[2]); accB[3] = fmaf(vB0, f1.y, accB[3]);
            accB[4] = fmaf(vB0, f2.x, accB[4]); accB[5] = fmaf(vB0, f2.y, accB[5]);
            accB[6] = fmaf(vB0, f3.x, accB[6]); accB[7] = fmaf(vB0, f3.y, accB[7]);
        }
        if (b1) {
            float2 f0 = __half22float2(*(const __half2*)&gB1.x);
            float2 f1 = __half22float2(*(const __half2*)&gB1.y);
            float2 f2 = __half22float2(*(const __half2*)&gB1.z);
            float2 f3 = __half22float2(*(const __half2*)&gB1.w);
            accB[0] = fmaf(vB1, f0.x, accB[0]); accB[1] = fmaf(vB1, f0.y, accB[1]);
            accB[2] = fmaf(vB1, f1.x, accB[2]); accB[3] = fmaf(vB1, f1.y, accB[3]);
            accB[4] = fmaf(vB1, f2.x, accB[4]); accB[5] = fmaf(vB1, f2.y, accB[5]);
            accB[6] = fmaf(vB1, f3.x, accB[6]); accB[7] = fmaf(vB1, f3.y, accB[7]);
        }
        eA += 2; eB += 2;
    }
    {
        f16x8 hA, hB;
#pragma unroll
        for (int j = 0; j < 8; ++j) { hA[j] = (f16)accA[j]; hB[j] = (f16)accB[j]; }
        *(f16x8*)&S16[rA * 72 + d8 * 8] = hA;
        *(f16x8*)&S16[rB * 72 + d8 * 8] = hB;
    }
    __syncthreads();

    // phase 2: MFMA epilogue. 8 waves x 16 rows -> 128 rows.
    int m = lane & 15, quad = lane >> 4;
    int rowbase = b * BROWS;
    int m0 = w * 16;
    f32x4 C[4] = {{0.f,0.f,0.f,0.f},{0.f,0.f,0.f,0.f},{0.f,0.f,0.f,0.f},{0.f,0.f,0.f,0.f}};
#pragma unroll
    for (int kk = 0; kk < 2; ++kk) {
        f16x8 A = *(const f16x8*)&S16[(m0 + m) * 72 + kk * 32 + quad * 8];
#pragma unroll
        for (int nt = 0; nt < 4; ++nt) {
            f16x8 B = *(const f16x8*)&Wl[(nt * 16 + m) * 72 + kk * 32 + quad * 8];
            C[nt] = __builtin_amdgcn_mfma_f32_16x16x32_f16(A, B, C[nt], 0, 0, 0);
        }
    }
#pragma unroll
    for (int nt = 0; nt < 4; ++nt) {
        float bv = bias[nt * 16 + m];
#pragma unroll
        for (int r = 0; r < 4; ++r) {
            int orow = rowbase + m0 + quad * 4 + r;
            float o = C[nt][r] + bv;
            o = o > 0.f ? o : 0.2f * o;
            if (orow < NTOT) {
                __half hh = __float2half(o);
                ego_out[(size_t)orow * EMB + nt * 16 + m] = *(u16*)&hh;
            }
        }
    }
}

// ---------------------------------------------------------------------------
// out[i][:] += l2norm(ego_f16[users[i]][:])
// ---------------------------------------------------------------------------
__global__ __launch_bounds__(256) void k_accum(const __half* __restrict__ ego,
                                               const int* __restrict__ users,
                                               float* __restrict__ out) {
    int t = blockIdx.x * 256 + threadIdx.x;
    int w = t >> 6, lane = t & 63;
    int u = users[w];
    float x = __half2float(ego[(size_t)u * EMB + lane]);
    float ss = x * x;
#pragma unroll
    for (int off = 32; off; off >>= 1) ss += __shfl_xor(ss, off);
    float n = sqrtf(ss);
    out[w * EMB + lane] += x / fmaxf(n, 1e-12f);
}

// ---------------------------------------------------------------------------
extern "C" void kernel_launch(void* const* d_in, const int* in_sizes, int n_in,
                              void* d_out, int out_size, void* d_ws, size_t ws_size,
                              hipStream_t stream) {
    const int*   users = (const int*)d_in[0];
    const int*   rows  = (const int*)d_in[1];
    const int*   cols  = (const int*)d_in[2];
    const float* vals  = (const float*)d_in[3];
    const float* ue    = (const float*)d_in[4];
    const float* ie    = (const float*)d_in[5];
    const float* Ws[3] = {(const float*)d_in[6], (const float*)d_in[8], (const float*)d_in[10]};
    const float* bs[3] = {(const float*)d_in[7], (const float*)d_in[9], (const float*)d_in[11]};
    float* out = (float*)d_out;

    // workspace layout (bytes, all 16B-aligned) — identical to round-0 footprint
    char* p = (char*)d_ws;
    f16*  egoA  = (f16*)p;  p += (size_t)NTOT * EMB * 2;        // 19.2 MB
    f16*  egoB  = (f16*)p;  p += (size_t)NTOT * EMB * 2;        // 19.2 MB
    int2* bbuf  = (int2*)p; p += (size_t)NB * BCAP * 8;         // 28.2 MB
    int*  bcnt  = (int*)p;  p += (size_t)NB * 16 * 4;           // 75 KB (line-padded)

    hipMemsetAsync(bcnt, 0, (size_t)NB * 16 * 4, stream);
    // fused init: ego build + layer-0 out copy, one dispatch
    k_init<<<EGO_BLKS + (BATCH * EMB) / 256, 256, 0, stream>>>(
        (const float4*)ue, (const float4*)ie, (uint2*)egoA, ue, users, out);

    // bucket by row>>7 (once, reused 3x), double-window, 16 waves/block
    k_bucket<<<(NNZ + WIN - 1) / WIN, 1024, 0, stream>>>(rows, cols, vals, bcnt, bbuf);

    // layer 3 only needs user rows -> only the first 391 buckets
    const int grids[3] = {NB, NB, (N_USER + BROWS - 1) / BROWS};
    f16* bufs[2] = {egoA, egoB};
    for (int l = 0; l < 3; ++l) {
        const f16* src = bufs[l & 1];
        f16*       dst = bufs[(l + 1) & 1];
        k_fused<<<grids[l], 512, 0, stream>>>(bcnt, bbuf, src, Ws[l], bs[l], (u16*)dst);
        k_accum<<<(BATCH * EMB) / 256, 256, 0, stream>>>((const __half*)dst, users, out);
    }
}